// Round 25
// baseline (3273.734 us; speedup 1.0000x reference)
//
#include <hip/hip_runtime.h>
#include <hip/hip_bf16.h>

#define B_ 128
#define T_ 1024
#define E_ 32
#define H_ 100
#define C_ 20
#define M_ (B_*T_)   // 131072

typedef __attribute__((ext_vector_type(8))) short bf16x8v;
typedef __attribute__((ext_vector_type(4))) float f32x4v;
typedef __attribute__((ext_vector_type(2))) _Float16 h2v;
typedef unsigned short u16;
typedef unsigned int u32;

static __device__ __forceinline__ short f2b(float x) {   // float -> bf16 bits
  union { __hip_bfloat16 b; short s; } u;
  u.b = __float2bfloat16(x);
  return u.s;
}
static __device__ __forceinline__ float b2f(u16 x) {     // bf16 bits -> float
  return __uint_as_float(((u32)x) << 16);
}

#if __has_builtin(__builtin_amdgcn_fdot2)
#define FDOT2(w, p, c) __builtin_amdgcn_fdot2((w), (p), (c), false)
#else
static __device__ __forceinline__ float FDOT2(h2v w, h2v p, float c) {
  return fmaf((float)w[1], (float)p[1], fmaf((float)w[0], (float)p[0], c));
}
#endif

// Counted barrier: LDS-producer drain + raw barrier, WITHOUT the vmcnt(0)
// drain __syncthreads emits (r21: -77us/dispatch on the scan).
#define WGBAR() do {                                        \
    asm volatile("s_waitcnt lgkmcnt(0)" ::: "memory");      \
    __builtin_amdgcn_s_barrier();                           \
    __builtin_amdgcn_sched_barrier(0);                      \
  } while (0)

// ---------------- embedding lookup ----------------
__global__ void embed_k(const int* __restrict__ tok, const float* __restrict__ emb,
                        float* __restrict__ x0) {
  int idx = blockIdx.x * 256 + threadIdx.x;   // over M_*E_ = 4194304
  int bt = idx >> 5;
  int e  = idx & 31;
  x0[idx] = emb[tok[bt] * E_ + e];
}

// ---------------- bf16 MFMA GEMM (r23 BM=128 version, kept) ----------------
template<int ABF, int OBF>
__global__ __launch_bounds__(256) void gemm_mfma_t(
    const void* __restrict__ Av, const float* __restrict__ W,
    const float* __restrict__ b1, const float* __restrict__ b2,
    void* __restrict__ Cv, int K, int N, int ldc)
{
  __shared__ short as[128 * 40];  // [row][k] pad 40
  __shared__ short ws[64 * 40];   // [col][k]
  const float* Af = (const float*)Av;
  const u16*   Ab = (const u16*)Av;
  float* Cf = (float*)Cv;
  u16*   Cb = (u16*)Cv;
  int tid = threadIdx.x, lane = tid & 63, w = tid >> 6;
  int lr = lane & 15, lq = lane >> 4;
  size_t m0 = (size_t)blockIdx.x * 128;
  int n0 = blockIdx.y * 64;
  int wsrow = tid >> 2;           // B staging row 0..63
  int wsk = (tid & 3) * 8;        // B staging k offset
  bool wok = (n0 + wsrow) < N;
  f32x4v acc[8];
  #pragma unroll
  for (int r = 0; r < 8; ++r) acc[r] = (f32x4v){0.f, 0.f, 0.f, 0.f};
  int ksteps = (K + 31) / 32;
  for (int ks = 0; ks < ksteps; ++ks) {
    int kk = ks * 32;
    #pragma unroll
    for (int q = 0; q < 2; ++q) {
      int slot = tid + q * 256;
      int ar = slot >> 2, ak = (slot & 3) * 8;
      size_t arow = (m0 + ar) * (size_t)K;
      bf16x8v av;
      if (kk + ak + 7 < K) {
        if (ABF) {
          av = *(const bf16x8v*)(Ab + arow + kk + ak);
        } else {
          float4 a0 = *(const float4*)(Af + arow + kk + ak);
          float4 a1 = *(const float4*)(Af + arow + kk + ak + 4);
          av[0]=f2b(a0.x); av[1]=f2b(a0.y); av[2]=f2b(a0.z); av[3]=f2b(a0.w);
          av[4]=f2b(a1.x); av[5]=f2b(a1.y); av[6]=f2b(a1.z); av[7]=f2b(a1.w);
        }
      } else {
        #pragma unroll
        for (int j = 0; j < 8; ++j) {
          int k = kk + ak + j;
          av[j] = (k < K) ? (ABF ? (short)Ab[arow + k] : f2b(Af[arow + k])) : (short)0;
        }
      }
      *(bf16x8v*)&as[ar * 40 + ak] = av;
    }
    {
      bf16x8v wv;
      if (wok && kk + wsk + 7 < K) {
        const float* Wp = W + (size_t)(n0 + wsrow) * K + wsk;
        float4 w0 = *(const float4*)(Wp + kk);
        float4 w1 = *(const float4*)(Wp + kk + 4);
        wv[0]=f2b(w0.x); wv[1]=f2b(w0.y); wv[2]=f2b(w0.z); wv[3]=f2b(w0.w);
        wv[4]=f2b(w1.x); wv[5]=f2b(w1.y); wv[6]=f2b(w1.z); wv[7]=f2b(w1.w);
      } else {
        #pragma unroll
        for (int j = 0; j < 8; ++j) {
          int k = kk + wsk + j;
          wv[j] = (wok && k < K) ? f2b(W[(size_t)(n0 + wsrow) * K + k]) : (short)0;
        }
      }
      *(bf16x8v*)&ws[wsrow * 40 + wsk] = wv;
    }
    __syncthreads();
    bf16x8v bf = *(const bf16x8v*)&ws[(16 * w + lr) * 40 + 8 * lq];
    #pragma unroll
    for (int r = 0; r < 8; ++r) {
      bf16x8v af = *(const bf16x8v*)&as[(16 * r + lr) * 40 + 8 * lq];
      acc[r] = __builtin_amdgcn_mfma_f32_16x16x32_bf16(af, bf, acc[r], 0, 0, 0);
    }
    __syncthreads();
  }
  int col = n0 + 16 * w + lr;
  if (col < N) {
    float bv = (b1 ? b1[col] : 0.f) + (b2 ? b2[col] : 0.f);
    #pragma unroll
    for (int r = 0; r < 8; ++r)
      #pragma unroll
      for (int rg = 0; rg < 4; ++rg) {
        size_t off = (m0 + 16 * r + 4 * lq + rg) * (size_t)ldc + col;
        float v = acc[r][rg] + bv;
        if (OBF) Cb[off] = (u16)f2b(v); else Cf[off] = v;
      }
  }
}

// ---------------- LSTM scan: r21 structure, TWO problems per WG -------------
// r24 post-mortem: load-depth (r20), LDS-load (r22), store-batch (r24) all
// neutral/negative around r21's 746us -> residual is the serial phase chain
// with all 8 waves lockstepped in the SAME phase of the SAME problem (only
// 2 waves/SIMD, one dependency chain). Fix: co-schedule the fwd+bwd scans of
// one batch in one 1024-thread WG (tid>>9 = problem slot). Barriers couple
// them but each SIMD now holds 4 waves / 2 INDEPENDENT chains -> A's chain
// stall overlaps B's issue. LDS arrays duplicated per slot.
__global__ __launch_bounds__(1024, 1) void lstm_scan(
    const u16* __restrict__ xp,
    const float* __restrict__ WhhF, const float* __restrict__ WhhR,
    const float* __restrict__ h0, const float* __restrict__ c0, // [4][B][H]
    const int* __restrict__ seqlen,   // null => no mask
    u16* __restrict__ outbuf,         // [B][T][200] bf16, dir*100 offset
    int layer)
{
  int tid = threadIdx.x;
  int pr = tid >> 9;                // problem slot 0/1 (= dir)
  int tidl = tid & 511;
  int b = blockIdx.x;               // batch
  int dir = pr;
  const float* Whh = dir ? WhhR : WhhF;
  const u16* xpp = xp + ((size_t)dir * B_ + b) * T_ * 400;
  const float* h0p = h0 + ((size_t)(2 * layer + dir) * B_ + b) * H_;
  const float* c0p = c0 + ((size_t)(2 * layer + dir) * B_ + b) * H_;
  __shared__ __align__(16) float gsh[2][400];
  __shared__ __align__(16) _Float16 hph[2][112];   // h as f16; [100..111] = 0
  bool act = (tidl < 400);
  int r = tidl >> 1, half = tidl & 1;
  int bu = half * 24;   // base k-pair (u32) index
  u32 w0p[28], w1p[28];
  if (act) {
    const float* r0 = Whh + (size_t)(2 * r) * H_;
    const float* r1 = Whh + (size_t)(2 * r + 1) * H_;
    #pragma unroll
    for (int j = 0; j < 28; ++j) {
      int kp = bu + j;
      bool rl = half ? (j < 26) : (j < 24);
      int k = 2 * kp;
      float a0 = (rl && k < 100) ? r0[k] : 0.f;
      float a1 = (rl && k + 1 < 100) ? r0[k + 1] : 0.f;
      float b0 = (rl && k < 100) ? r1[k] : 0.f;
      float b1 = (rl && k + 1 < 100) ? r1[k + 1] : 0.f;
      w0p[j] = __builtin_bit_cast(u32, (h2v){(_Float16)a0, (_Float16)a1});
      w1p[j] = __builtin_bit_cast(u32, (h2v){(_Float16)b0, (_Float16)b1});
    }
    #pragma unroll
    for (int j = 0; j < 28; ++j)
      asm volatile("" : "+v"(w0p[j]), "+v"(w1p[j]));
  }
  if (tidl < 112) hph[pr][tidl] = (_Float16)((tidl < H_) ? h0p[tidl] : 0.f);
  float c = (tidl < H_) ? c0p[tidl] : 0.f;
  int sl = seqlen ? seqlen[b] : T_;
  __syncthreads();
  int tstep = dir ? -1 : 1;
  int t0 = dir ? (T_ - 1) : 0;
  ushort2 xc = make_ushort2(0, 0), xn = make_ushort2(0, 0), x2 = make_ushort2(0, 0);
  bool ldx = act && !half;
  if (ldx) {
    xc = *(const ushort2*)(xpp + (size_t)t0 * 400 + 2 * r);
    xn = *(const ushort2*)(xpp + (size_t)(t0 + tstep) * 400 + 2 * r);
    x2 = *(const ushort2*)(xpp + (size_t)(t0 + 2 * tstep) * 400 + 2 * r);
  }
  for (int tt = 0; tt < T_; ++tt) {
    int t = t0 + tstep * tt;
    ushort2 x3 = make_ushort2(0, 0);
    if (ldx && tt + 3 < T_)
      x3 = *(const ushort2*)(xpp + (size_t)(t + 3 * tstep) * 400 + 2 * r);
    if (act) {
      float a0 = half ? 0.f : b2f(xc.x);
      float a1 = half ? 0.f : b2f(xc.y);
      #pragma unroll
      for (int q = 0; q < 7; ++q) {
        f32x4v hp = ((const f32x4v*)&hph[pr][0])[6 * half + q];  // 2 addrs/wave
        #pragma unroll
        for (int i = 0; i < 4; ++i) {
          h2v p = __builtin_bit_cast(h2v, hp[i]);
          a0 = FDOT2(__builtin_bit_cast(h2v, w0p[4 * q + i]), p, a0);
          a1 = FDOT2(__builtin_bit_cast(h2v, w1p[4 * q + i]), p, a1);
        }
      }
      a0 += __shfl_xor(a0, 1);   // combine k-halves (adjacent lanes)
      a1 += __shfl_xor(a1, 1);
      if (!half) *(float2*)&gsh[pr][2 * r] = make_float2(a0, a1);
    }
    WGBAR();
    if (tidl < H_) {
      float gi = gsh[pr][tidl], gf = gsh[pr][H_ + tidl];
      float gg = gsh[pr][2 * H_ + tidl], go = gsh[pr][3 * H_ + tidl];
      float si = 1.f / (1.f + __expf(-gi));
      float sf = 1.f / (1.f + __expf(-gf));
      float so = 1.f / (1.f + __expf(-go));
      float tg = 1.f - 2.f / (1.f + __expf(2.f * gg));
      c = fmaf(sf, c, si * tg);
      float tc = 1.f - 2.f / (1.f + __expf(2.f * c));
      float h = so * tc;
      hph[pr][tidl] = (_Float16)h;
      outbuf[((size_t)b * T_ + t) * 200 + dir * H_ + tidl] = (t < sl) ? (u16)f2b(h) : (u16)0;
    }
    WGBAR();
    xc = xn; xn = x2; x2 = x3;
  }
}

// ---------------- CRF with LDS ring staging (r15 winner, unchanged) --------
__global__ __launch_bounds__(64) void crf_k(
    const float* __restrict__ f, const float* __restrict__ g,
    float* __restrict__ alpha, float* __restrict__ beta)
{
  int wg = blockIdx.x;
  int lane = threadIdx.x;
  __shared__ __align__(16) float gl[4][400];   // ring: row r -> slot r&3
  __shared__ __align__(16) float aw[20];       // alpha: a[t-1]; beta: f[t+1]+b[t+1]
  bool stv = lane < 50;
  int p0 = 8 * lane;                           // this lane stages floats [p0,p0+8)
  float4 rA0, rA1, rB0, rB1;                   // in-flight staged row (reg ring)

  if (wg < B_) {
    int b = wg;
    const float* fp = f + (size_t)b * T_ * C_;
    const float* gp = g + (size_t)b * T_ * C_ * C_;
    float* ap = alpha + (size_t)b * T_ * C_;
    if (lane < C_) {
      float a0 = fp[lane];
      ap[lane] = a0;
      aw[lane] = a0;
    }
    if (stv) {
      float4 v0 = *(const float4*)(gp + 400 + p0);
      float4 v1 = *(const float4*)(gp + 404 + p0);
      *(float4*)&gl[1 & 3][p0] = v0;  *(float4*)&gl[1 & 3][p0 + 4] = v1;
      v0 = *(const float4*)(gp + 800 + p0);
      v1 = *(const float4*)(gp + 804 + p0);
      *(float4*)&gl[2 & 3][p0] = v0;  *(float4*)&gl[2 & 3][p0 + 4] = v1;
      rA0 = *(const float4*)(gp + 1200 + p0);       // row 3 in flight
      rA1 = *(const float4*)(gp + 1204 + p0);
    }
    for (int t = 1; t < T_; ++t) {
      if (stv && (t + 3 < T_)) {
        rB0 = *(const float4*)(gp + (size_t)(t + 3) * 400 + p0);
        rB1 = *(const float4*)(gp + (size_t)(t + 3) * 400 + p0 + 4);
      }
      if (lane < C_) {
        const float* gr = &gl[t & 3][0];
        float ft = fp[(size_t)t * C_ + lane];
        float awv[20];
        #pragma unroll
        for (int q = 0; q < 5; ++q)
          *(f32x4v*)&awv[4 * q] = ((const f32x4v*)aw)[q];
        float s[20];
        #pragma unroll
        for (int i = 0; i < 20; ++i)
          s[i] = awv[i] + gr[i * 20 + lane];
        float m4[5];
        #pragma unroll
        for (int q = 0; q < 5; ++q)
          m4[q] = fmaxf(fmaxf(s[4*q], s[4*q+1]), fmaxf(s[4*q+2], s[4*q+3]));
        float m = fmaxf(fmaxf(m4[0], m4[1]), fmaxf(fmaxf(m4[2], m4[3]), m4[4]));
        float e4[5];
        #pragma unroll
        for (int q = 0; q < 5; ++q) {
          float e0 = __expf(s[4*q] - m),   e1 = __expf(s[4*q+1] - m);
          float e2 = __expf(s[4*q+2] - m), e3 = __expf(s[4*q+3] - m);
          e4[q] = (e0 + e1) + (e2 + e3);
        }
        float sum = (e4[0] + e4[1]) + ((e4[2] + e4[3]) + e4[4]);
        float an = ft + m + __logf(sum);
        ap[(size_t)t * C_ + lane] = an;
        aw[lane] = an;
      }
      if (stv && (t + 2 < T_)) {
        *(float4*)&gl[(t + 2) & 3][p0] = rA0;
        *(float4*)&gl[(t + 2) & 3][p0 + 4] = rA1;
      }
      rA0 = rB0; rA1 = rB1;
    }
  } else {
    int b = wg - B_;
    const float* fp = f + (size_t)b * T_ * C_;
    const float* gp = g + (size_t)b * T_ * C_ * C_;
    float* bp = beta + (size_t)b * T_ * C_;
    if (lane < C_) {
      bp[(size_t)(T_ - 1) * C_ + lane] = 0.f;
      aw[lane] = fp[(size_t)(T_ - 1) * C_ + lane];
    }
    if (stv) {
      float4 v0 = *(const float4*)(gp + (size_t)(T_ - 1) * 400 + p0);
      float4 v1 = *(const float4*)(gp + (size_t)(T_ - 1) * 400 + p0 + 4);
      *(float4*)&gl[(T_ - 1) & 3][p0] = v0;  *(float4*)&gl[(T_ - 1) & 3][p0 + 4] = v1;
      v0 = *(const float4*)(gp + (size_t)(T_ - 2) * 400 + p0);
      v1 = *(const float4*)(gp + (size_t)(T_ - 2) * 400 + p0 + 4);
      *(float4*)&gl[(T_ - 2) & 3][p0] = v0;  *(float4*)&gl[(T_ - 2) & 3][p0 + 4] = v1;
      rA0 = *(const float4*)(gp + (size_t)(T_ - 3) * 400 + p0);
      rA1 = *(const float4*)(gp + (size_t)(T_ - 3) * 400 + p0 + 4);
    }
    for (int u = 1; u < T_; ++u) {
      int t = T_ - 1 - u;
      int r = t + 1;
      if (stv && (r - 3 >= 1)) {
        rB0 = *(const float4*)(gp + (size_t)(r - 3) * 400 + p0);
        rB1 = *(const float4*)(gp + (size_t)(r - 3) * 400 + p0 + 4);
      }
      if (lane < C_) {
        const float* gr = &gl[r & 3][lane * 20];
        float fcur = fp[(size_t)t * C_ + lane];
        float awv[20];
        #pragma unroll
        for (int q = 0; q < 5; ++q)
          *(f32x4v*)&awv[4 * q] = ((const f32x4v*)aw)[q];
        float s[20];
        #pragma unroll
        for (int q = 0; q < 5; ++q) {
          f32x4v gq = *(const f32x4v*)&gr[4 * q];
          s[4*q]   = awv[4*q]   + gq[0];
          s[4*q+1] = awv[4*q+1] + gq[1];
          s[4*q+2] = awv[4*q+2] + gq[2];
          s[4*q+3] = awv[4*q+3] + gq[3];
        }
        float m4[5];
        #pragma unroll
        for (int q = 0; q < 5; ++q)
          m4[q] = fmaxf(fmaxf(s[4*q], s[4*q+1]), fmaxf(s[4*q+2], s[4*q+3]));
        float m = fmaxf(fmaxf(m4[0], m4[1]), fmaxf(fmaxf(m4[2], m4[3]), m4[4]));
        float e4[5];
        #pragma unroll
        for (int q = 0; q < 5; ++q) {
          float e0 = __expf(s[4*q] - m),   e1 = __expf(s[4*q+1] - m);
          float e2 = __expf(s[4*q+2] - m), e3 = __expf(s[4*q+3] - m);
          e4[q] = (e0 + e1) + (e2 + e3);
        }
        float sum = (e4[0] + e4[1]) + ((e4[2] + e4[3]) + e4[4]);
        float bn = m + __logf(sum);
        bp[(size_t)t * C_ + lane] = bn;
        aw[lane] = fcur + bn;
      }
      if (stv && (r - 2 >= 1)) {
        *(float4*)&gl[(r - 2) & 3][p0] = rA0;
        *(float4*)&gl[(r - 2) & 3][p0 + 4] = rA1;
      }
      rA0 = rB0; rA1 = rB1;
    }
  }
}

// ---------------- logZ per batch ----------------
__global__ void logz_k(const float* __restrict__ alpha, float* __restrict__ lz) {
  int b = blockIdx.x; int lane = threadIdx.x;
  float a = (lane < C_) ? alpha[((size_t)b * T_ + (T_ - 1)) * C_ + lane] : -3.0e38f;
  float m = a;
  #pragma unroll
  for (int o = 32; o > 0; o >>= 1) m = fmaxf(m, __shfl_xor(m, o));
  float e = (lane < C_) ? __expf(a - m) : 0.f;
  #pragma unroll
  for (int o = 32; o > 0; o >>= 1) e += __shfl_xor(e, o);
  if (lane == 0) lz[b] = m + __logf(e);
}

// ---------------- marginals = exp(alpha+beta-logZ) ----------------
__global__ void marg_k(const float* __restrict__ alpha, const float* __restrict__ beta,
                       const float* __restrict__ lz, float* __restrict__ out0) {
  size_t idx = (size_t)blockIdx.x * 256 + threadIdx.x;
  int b = (int)(idx / (T_ * C_));
  out0[idx] = __expf(alpha[idx] + beta[idx] - lz[b]);
}

extern "C" void kernel_launch(void* const* d_in, const int* in_sizes, int n_in,
                              void* d_out, int out_size, void* d_ws, size_t ws_size,
                              hipStream_t stream) {
  const int*   tok   = (const int*)d_in[0];
  const int*   seq   = (const int*)d_in[1];
  const float* emb   = (const float*)d_in[2];
  const float* Wih0  = (const float*)d_in[3];
  const float* Whh0  = (const float*)d_in[4];
  const float* bih0  = (const float*)d_in[5];
  const float* bhh0  = (const float*)d_in[6];
  const float* Wih0r = (const float*)d_in[7];
  const float* Whh0r = (const float*)d_in[8];
  const float* bih0r = (const float*)d_in[9];
  const float* bhh0r = (const float*)d_in[10];
  const float* Wih1  = (const float*)d_in[11];
  const float* Whh1  = (const float*)d_in[12];
  const float* bih1  = (const float*)d_in[13];
  const float* bhh1  = (const float*)d_in[14];
  const float* Wih1r = (const float*)d_in[15];
  const float* Whh1r = (const float*)d_in[16];
  const float* bih1r = (const float*)d_in[17];
  const float* bhh1r = (const float*)d_in[18];
  const float* fW    = (const float*)d_in[19];
  const float* fb    = (const float*)d_in[20];
  const float* gW    = (const float*)d_in[21];
  const float* gb    = (const float*)d_in[22];
  const float* h0    = (const float*)d_in[23];
  const float* c0    = (const float*)d_in[24];

  float* ws = (float*)d_ws;
  float* x0  = ws;                          // 4,194,304 floats
  u16*   xp  = (u16*)(ws + 4194304);        // 104,857,600 bf16
  u16*   x1  = (u16*)(ws + 109051904);      // 26,214,400 bf16
  float* lz  = ws + 135266304;              // 128 floats

  float* out   = (float*)d_out;
  float* f_out = out + 2621440;
  float* g_out = out + 5242880;
  float* a_out = out + 57671680;
  float* b_out = out + 60293120;

  embed_k<<<16384, 256, 0, stream>>>(tok, emb, x0);

  dim3 g400(1024, 7), g20(1024, 1);
  // layer 0 input projections (K=32): fp32 A -> bf16 xp
  gemm_mfma_t<0,1><<<g400, 256, 0, stream>>>(x0, Wih0,  bih0,  bhh0,  xp,                    32, 400, 400);
  gemm_mfma_t<0,1><<<g400, 256, 0, stream>>>(x0, Wih0r, bih0r, bhh0r, xp + (size_t)52428800, 32, 400, 400);
  lstm_scan<<<128, 1024, 0, stream>>>(xp, Whh0, Whh0r, h0, c0, nullptr, x1, 0);
  // layer 1 input projections (K=200): bf16 A -> bf16 xp
  gemm_mfma_t<1,1><<<g400, 256, 0, stream>>>(x1, Wih1,  bih1,  bhh1,  xp,                    200, 400, 400);
  gemm_mfma_t<1,1><<<g400, 256, 0, stream>>>(x1, Wih1r, bih1r, bhh1r, xp + (size_t)52428800, 200, 400, 400);
  lstm_scan<<<128, 1024, 0, stream>>>(xp, Whh1, Whh1r, h0, c0, seq, x1, 1);
  // emissions + transitions: bf16 A -> fp32 outputs
  gemm_mfma_t<1,0><<<g20,  256, 0, stream>>>(x1, fW, fb, nullptr, f_out, 200, 20,  20);
  gemm_mfma_t<1,0><<<g400, 256, 0, stream>>>(x1, gW, gb, nullptr, g_out, 200, 400, 400);
  // CRF forward/backward
  crf_k<<<256, 64, 0, stream>>>(f_out, g_out, a_out, b_out);
  logz_k<<<128, 64, 0, stream>>>(a_out, lz);
  marg_k<<<10240, 256, 0, stream>>>(a_out, b_out, lz, out);
}

// Round 26
// 2877.622 us; speedup vs baseline: 1.1377x; 1.1377x over previous
//
#include <hip/hip_runtime.h>
#include <hip/hip_bf16.h>

#define B_ 128
#define T_ 1024
#define E_ 32
#define H_ 100
#define C_ 20
#define M_ (B_*T_)   // 131072

typedef __attribute__((ext_vector_type(8))) short bf16x8v;
typedef __attribute__((ext_vector_type(4))) float f32x4v;
typedef __attribute__((ext_vector_type(2))) _Float16 h2v;
typedef unsigned short u16;
typedef unsigned int u32;

static __device__ __forceinline__ short f2b(float x) {   // float -> bf16 bits
  union { __hip_bfloat16 b; short s; } u;
  u.b = __float2bfloat16(x);
  return u.s;
}
static __device__ __forceinline__ float b2f(u16 x) {     // bf16 bits -> float
  return __uint_as_float(((u32)x) << 16);
}

#if __has_builtin(__builtin_amdgcn_fdot2)
#define FDOT2(w, p, c) __builtin_amdgcn_fdot2((w), (p), (c), false)
#else
static __device__ __forceinline__ float FDOT2(h2v w, h2v p, float c) {
  return fmaf((float)w[1], (float)p[1], fmaf((float)w[0], (float)p[0], c));
}
#endif

// Counted barrier: LDS-producer drain + raw barrier, WITHOUT the vmcnt(0)
// drain __syncthreads emits (r21: -77us/dispatch on the scan).
#define WGBAR() do {                                        \
    asm volatile("s_waitcnt lgkmcnt(0)" ::: "memory");      \
    __builtin_amdgcn_s_barrier();                           \
    __builtin_amdgcn_sched_barrier(0);                      \
  } while (0)

// ---------------- embedding lookup ----------------
__global__ void embed_k(const int* __restrict__ tok, const float* __restrict__ emb,
                        float* __restrict__ x0) {
  int idx = blockIdx.x * 256 + threadIdx.x;   // over M_*E_ = 4194304
  int bt = idx >> 5;
  int e  = idx & 31;
  x0[idx] = emb[tok[bt] * E_ + e];
}

// ---------------- bf16 MFMA GEMM (r23 BM=128 version, kept) ----------------
template<int ABF, int OBF>
__global__ __launch_bounds__(256) void gemm_mfma_t(
    const void* __restrict__ Av, const float* __restrict__ W,
    const float* __restrict__ b1, const float* __restrict__ b2,
    void* __restrict__ Cv, int K, int N, int ldc)
{
  __shared__ short as[128 * 40];  // [row][k] pad 40
  __shared__ short ws[64 * 40];   // [col][k]
  const float* Af = (const float*)Av;
  const u16*   Ab = (const u16*)Av;
  float* Cf = (float*)Cv;
  u16*   Cb = (u16*)Cv;
  int tid = threadIdx.x, lane = tid & 63, w = tid >> 6;
  int lr = lane & 15, lq = lane >> 4;
  size_t m0 = (size_t)blockIdx.x * 128;
  int n0 = blockIdx.y * 64;
  int wsrow = tid >> 2;           // B staging row 0..63
  int wsk = (tid & 3) * 8;        // B staging k offset
  bool wok = (n0 + wsrow) < N;
  f32x4v acc[8];
  #pragma unroll
  for (int r = 0; r < 8; ++r) acc[r] = (f32x4v){0.f, 0.f, 0.f, 0.f};
  int ksteps = (K + 31) / 32;
  for (int ks = 0; ks < ksteps; ++ks) {
    int kk = ks * 32;
    #pragma unroll
    for (int q = 0; q < 2; ++q) {
      int slot = tid + q * 256;
      int ar = slot >> 2, ak = (slot & 3) * 8;
      size_t arow = (m0 + ar) * (size_t)K;
      bf16x8v av;
      if (kk + ak + 7 < K) {
        if (ABF) {
          av = *(const bf16x8v*)(Ab + arow + kk + ak);
        } else {
          float4 a0 = *(const float4*)(Af + arow + kk + ak);
          float4 a1 = *(const float4*)(Af + arow + kk + ak + 4);
          av[0]=f2b(a0.x); av[1]=f2b(a0.y); av[2]=f2b(a0.z); av[3]=f2b(a0.w);
          av[4]=f2b(a1.x); av[5]=f2b(a1.y); av[6]=f2b(a1.z); av[7]=f2b(a1.w);
        }
      } else {
        #pragma unroll
        for (int j = 0; j < 8; ++j) {
          int k = kk + ak + j;
          av[j] = (k < K) ? (ABF ? (short)Ab[arow + k] : f2b(Af[arow + k])) : (short)0;
        }
      }
      *(bf16x8v*)&as[ar * 40 + ak] = av;
    }
    {
      bf16x8v wv;
      if (wok && kk + wsk + 7 < K) {
        const float* Wp = W + (size_t)(n0 + wsrow) * K + wsk;
        float4 w0 = *(const float4*)(Wp + kk);
        float4 w1 = *(const float4*)(Wp + kk + 4);
        wv[0]=f2b(w0.x); wv[1]=f2b(w0.y); wv[2]=f2b(w0.z); wv[3]=f2b(w0.w);
        wv[4]=f2b(w1.x); wv[5]=f2b(w1.y); wv[6]=f2b(w1.z); wv[7]=f2b(w1.w);
      } else {
        #pragma unroll
        for (int j = 0; j < 8; ++j) {
          int k = kk + wsk + j;
          wv[j] = (wok && k < K) ? f2b(W[(size_t)(n0 + wsrow) * K + k]) : (short)0;
        }
      }
      *(bf16x8v*)&ws[wsrow * 40 + wsk] = wv;
    }
    __syncthreads();
    bf16x8v bf = *(const bf16x8v*)&ws[(16 * w + lr) * 40 + 8 * lq];
    #pragma unroll
    for (int r = 0; r < 8; ++r) {
      bf16x8v af = *(const bf16x8v*)&as[(16 * r + lr) * 40 + 8 * lq];
      acc[r] = __builtin_amdgcn_mfma_f32_16x16x32_bf16(af, bf, acc[r], 0, 0, 0);
    }
    __syncthreads();
  }
  int col = n0 + 16 * w + lr;
  if (col < N) {
    float bv = (b1 ? b1[col] : 0.f) + (b2 ? b2[col] : 0.f);
    #pragma unroll
    for (int r = 0; r < 8; ++r)
      #pragma unroll
      for (int rg = 0; rg < 4; ++rg) {
        size_t off = (m0 + 16 * r + 4 * lq + rg) * (size_t)ldc + col;
        float v = acc[r][rg] + bv;
        if (OBF) Cb[off] = (u16)f2b(v); else Cf[off] = v;
      }
  }
}

// ---------------- LSTM scan: r21 structure + balanced phases ----------------
// REVERT of r24/r25 regressions to r21 (746us best), plus one change:
// uniform phase distribution. r21 packed the 200 dot-pairs into waves 0-6
// (SIMDs 0/1 carry 2 FULL dot-waves -> barrier waits on them) and ran the
// activation on tid<100 = waves 0-1 only (SIMDs 2/3 fully idle through the
// ~300cy transcendental chain). Now: 25 dot-pairs per wave (50 lanes/wave,
// shfl pairs stay adjacent) and 13 activation units per wave (u=wave*13+lane)
// -> every SIMD holds 2 active waves in BOTH phases, chains overlap.
__global__ __launch_bounds__(512, 1) void lstm_scan(
    const u16* __restrict__ xp,
    const float* __restrict__ WhhF, const float* __restrict__ WhhR,
    const float* __restrict__ h0, const float* __restrict__ c0, // [4][B][H]
    const int* __restrict__ seqlen,   // null => no mask
    u16* __restrict__ outbuf,         // [B][T][200] bf16, dir*100 offset
    int layer)
{
  int wg = blockIdx.x; int dir = wg & 1; int b = wg >> 1;
  int tid = threadIdx.x;
  int wv = tid >> 6, lane = tid & 63;
  const float* Whh = dir ? WhhR : WhhF;
  const u16* xpp = xp + ((size_t)dir * B_ + b) * T_ * 400;
  const float* h0p = h0 + ((size_t)(2 * layer + dir) * B_ + b) * H_;
  const float* c0p = c0 + ((size_t)(2 * layer + dir) * B_ + b) * H_;
  __shared__ __align__(16) float gsh[400];
  __shared__ __align__(16) _Float16 hph[112];   // h as f16; [100..111] = 0
  // dot mapping: 25 pairs/wave; pair p = wv*25 + (lane>>1), active (lane>>1)<25
  int pidx = lane >> 1, half = lane & 1;
  int r = wv * 25 + pidx;
  bool act = (pidx < 25);          // r < 200 guaranteed (wv<8 -> r<=199)
  int bu = half * 24;   // base k-pair (u32) index
  u32 w0p[28], w1p[28];
  if (act) {
    const float* r0 = Whh + (size_t)(2 * r) * H_;
    const float* r1 = Whh + (size_t)(2 * r + 1) * H_;
    #pragma unroll
    for (int j = 0; j < 28; ++j) {
      int kp = bu + j;
      bool rl = half ? (j < 26) : (j < 24);
      int k = 2 * kp;
      float a0 = (rl && k < 100) ? r0[k] : 0.f;
      float a1 = (rl && k + 1 < 100) ? r0[k + 1] : 0.f;
      float b0 = (rl && k < 100) ? r1[k] : 0.f;
      float b1 = (rl && k + 1 < 100) ? r1[k + 1] : 0.f;
      w0p[j] = __builtin_bit_cast(u32, (h2v){(_Float16)a0, (_Float16)a1});
      w1p[j] = __builtin_bit_cast(u32, (h2v){(_Float16)b0, (_Float16)b1});
    }
    #pragma unroll
    for (int j = 0; j < 28; ++j)
      asm volatile("" : "+v"(w0p[j]), "+v"(w1p[j]));
  }
  // activation mapping: unit u = wv*13 + lane, active lane<13 && u<100
  int au = wv * 13 + lane;
  bool actv = (lane < 13) && (au < 100);
  if (tid < 112) hph[tid] = (_Float16)((tid < H_) ? h0p[tid] : 0.f);
  float c = actv ? c0p[au] : 0.f;
  int sl = seqlen ? seqlen[b] : T_;
  __syncthreads();
  int tstep = dir ? -1 : 1;
  int t0 = dir ? (T_ - 1) : 0;
  ushort2 xc = make_ushort2(0, 0), xn = make_ushort2(0, 0), x2 = make_ushort2(0, 0);
  bool ldx = act && !half;
  if (ldx) {
    xc = *(const ushort2*)(xpp + (size_t)t0 * 400 + 2 * r);
    xn = *(const ushort2*)(xpp + (size_t)(t0 + tstep) * 400 + 2 * r);
    x2 = *(const ushort2*)(xpp + (size_t)(t0 + 2 * tstep) * 400 + 2 * r);
  }
  for (int tt = 0; tt < T_; ++tt) {
    int t = t0 + tstep * tt;
    ushort2 x3 = make_ushort2(0, 0);
    if (ldx && tt + 3 < T_)
      x3 = *(const ushort2*)(xpp + (size_t)(t + 3 * tstep) * 400 + 2 * r);
    if (act) {
      float a0 = half ? 0.f : b2f(xc.x);
      float a1 = half ? 0.f : b2f(xc.y);
      #pragma unroll
      for (int q = 0; q < 7; ++q) {
        f32x4v hp = ((const f32x4v*)hph)[6 * half + q];   // 2 addrs/wave -> free
        #pragma unroll
        for (int i = 0; i < 4; ++i) {
          h2v p = __builtin_bit_cast(h2v, hp[i]);
          a0 = FDOT2(__builtin_bit_cast(h2v, w0p[4 * q + i]), p, a0);
          a1 = FDOT2(__builtin_bit_cast(h2v, w1p[4 * q + i]), p, a1);
        }
      }
      a0 += __shfl_xor(a0, 1);   // combine k-halves (adjacent lanes)
      a1 += __shfl_xor(a1, 1);
      if (!half) *(float2*)&gsh[2 * r] = make_float2(a0, a1);
    }
    WGBAR();
    if (actv) {
      float gi = gsh[au], gf = gsh[H_ + au], gg = gsh[2 * H_ + au], go = gsh[3 * H_ + au];
      float si = 1.f / (1.f + __expf(-gi));
      float sf = 1.f / (1.f + __expf(-gf));
      float so = 1.f / (1.f + __expf(-go));
      float tg = 1.f - 2.f / (1.f + __expf(2.f * gg));
      c = fmaf(sf, c, si * tg);
      float tc = 1.f - 2.f / (1.f + __expf(2.f * c));
      float h = so * tc;
      hph[au] = (_Float16)h;
      outbuf[((size_t)b * T_ + t) * 200 + dir * H_ + au] = (t < sl) ? (u16)f2b(h) : (u16)0;
    }
    WGBAR();
    xc = xn; xn = x2; x2 = x3;
  }
}

// ---------------- CRF with LDS ring staging (r15 winner, unchanged) --------
__global__ __launch_bounds__(64) void crf_k(
    const float* __restrict__ f, const float* __restrict__ g,
    float* __restrict__ alpha, float* __restrict__ beta)
{
  int wg = blockIdx.x;
  int lane = threadIdx.x;
  __shared__ __align__(16) float gl[4][400];   // ring: row r -> slot r&3
  __shared__ __align__(16) float aw[20];       // alpha: a[t-1]; beta: f[t+1]+b[t+1]
  bool stv = lane < 50;
  int p0 = 8 * lane;                           // this lane stages floats [p0,p0+8)
  float4 rA0, rA1, rB0, rB1;                   // in-flight staged row (reg ring)

  if (wg < B_) {
    int b = wg;
    const float* fp = f + (size_t)b * T_ * C_;
    const float* gp = g + (size_t)b * T_ * C_ * C_;
    float* ap = alpha + (size_t)b * T_ * C_;
    if (lane < C_) {
      float a0 = fp[lane];
      ap[lane] = a0;
      aw[lane] = a0;
    }
    if (stv) {
      float4 v0 = *(const float4*)(gp + 400 + p0);
      float4 v1 = *(const float4*)(gp + 404 + p0);
      *(float4*)&gl[1 & 3][p0] = v0;  *(float4*)&gl[1 & 3][p0 + 4] = v1;
      v0 = *(const float4*)(gp + 800 + p0);
      v1 = *(const float4*)(gp + 804 + p0);
      *(float4*)&gl[2 & 3][p0] = v0;  *(float4*)&gl[2 & 3][p0 + 4] = v1;
      rA0 = *(const float4*)(gp + 1200 + p0);       // row 3 in flight
      rA1 = *(const float4*)(gp + 1204 + p0);
    }
    for (int t = 1; t < T_; ++t) {
      if (stv && (t + 3 < T_)) {
        rB0 = *(const float4*)(gp + (size_t)(t + 3) * 400 + p0);
        rB1 = *(const float4*)(gp + (size_t)(t + 3) * 400 + p0 + 4);
      }
      if (lane < C_) {
        const float* gr = &gl[t & 3][0];
        float ft = fp[(size_t)t * C_ + lane];
        float awv[20];
        #pragma unroll
        for (int q = 0; q < 5; ++q)
          *(f32x4v*)&awv[4 * q] = ((const f32x4v*)aw)[q];
        float s[20];
        #pragma unroll
        for (int i = 0; i < 20; ++i)
          s[i] = awv[i] + gr[i * 20 + lane];
        float m4[5];
        #pragma unroll
        for (int q = 0; q < 5; ++q)
          m4[q] = fmaxf(fmaxf(s[4*q], s[4*q+1]), fmaxf(s[4*q+2], s[4*q+3]));
        float m = fmaxf(fmaxf(m4[0], m4[1]), fmaxf(fmaxf(m4[2], m4[3]), m4[4]));
        float e4[5];
        #pragma unroll
        for (int q = 0; q < 5; ++q) {
          float e0 = __expf(s[4*q] - m),   e1 = __expf(s[4*q+1] - m);
          float e2 = __expf(s[4*q+2] - m), e3 = __expf(s[4*q+3] - m);
          e4[q] = (e0 + e1) + (e2 + e3);
        }
        float sum = (e4[0] + e4[1]) + ((e4[2] + e4[3]) + e4[4]);
        float an = ft + m + __logf(sum);
        ap[(size_t)t * C_ + lane] = an;
        aw[lane] = an;
      }
      if (stv && (t + 2 < T_)) {
        *(float4*)&gl[(t + 2) & 3][p0] = rA0;
        *(float4*)&gl[(t + 2) & 3][p0 + 4] = rA1;
      }
      rA0 = rB0; rA1 = rB1;
    }
  } else {
    int b = wg - B_;
    const float* fp = f + (size_t)b * T_ * C_;
    const float* gp = g + (size_t)b * T_ * C_ * C_;
    float* bp = beta + (size_t)b * T_ * C_;
    if (lane < C_) {
      bp[(size_t)(T_ - 1) * C_ + lane] = 0.f;
      aw[lane] = fp[(size_t)(T_ - 1) * C_ + lane];
    }
    if (stv) {
      float4 v0 = *(const float4*)(gp + (size_t)(T_ - 1) * 400 + p0);
      float4 v1 = *(const float4*)(gp + (size_t)(T_ - 1) * 400 + p0 + 4);
      *(float4*)&gl[(T_ - 1) & 3][p0] = v0;  *(float4*)&gl[(T_ - 1) & 3][p0 + 4] = v1;
      v0 = *(const float4*)(gp + (size_t)(T_ - 2) * 400 + p0);
      v1 = *(const float4*)(gp + (size_t)(T_ - 2) * 400 + p0 + 4);
      *(float4*)&gl[(T_ - 2) & 3][p0] = v0;  *(float4*)&gl[(T_ - 2) & 3][p0 + 4] = v1;
      rA0 = *(const float4*)(gp + (size_t)(T_ - 3) * 400 + p0);
      rA1 = *(const float4*)(gp + (size_t)(T_ - 3) * 400 + p0 + 4);
    }
    for (int u = 1; u < T_; ++u) {
      int t = T_ - 1 - u;
      int r = t + 1;
      if (stv && (r - 3 >= 1)) {
        rB0 = *(const float4*)(gp + (size_t)(r - 3) * 400 + p0);
        rB1 = *(const float4*)(gp + (size_t)(r - 3) * 400 + p0 + 4);
      }
      if (lane < C_) {
        const float* gr = &gl[r & 3][lane * 20];
        float fcur = fp[(size_t)t * C_ + lane];
        float awv[20];
        #pragma unroll
        for (int q = 0; q < 5; ++q)
          *(f32x4v*)&awv[4 * q] = ((const f32x4v*)aw)[q];
        float s[20];
        #pragma unroll
        for (int q = 0; q < 5; ++q) {
          f32x4v gq = *(const f32x4v*)&gr[4 * q];
          s[4*q]   = awv[4*q]   + gq[0];
          s[4*q+1] = awv[4*q+1] + gq[1];
          s[4*q+2] = awv[4*q+2] + gq[2];
          s[4*q+3] = awv[4*q+3] + gq[3];
        }
        float m4[5];
        #pragma unroll
        for (int q = 0; q < 5; ++q)
          m4[q] = fmaxf(fmaxf(s[4*q], s[4*q+1]), fmaxf(s[4*q+2], s[4*q+3]));
        float m = fmaxf(fmaxf(m4[0], m4[1]), fmaxf(fmaxf(m4[2], m4[3]), m4[4]));
        float e4[5];
        #pragma unroll
        for (int q = 0; q < 5; ++q) {
          float e0 = __expf(s[4*q] - m),   e1 = __expf(s[4*q+1] - m);
          float e2 = __expf(s[4*q+2] - m), e3 = __expf(s[4*q+3] - m);
          e4[q] = (e0 + e1) + (e2 + e3);
        }
        float sum = (e4[0] + e4[1]) + ((e4[2] + e4[3]) + e4[4]);
        float bn = m + __logf(sum);
        bp[(size_t)t * C_ + lane] = bn;
        aw[lane] = fcur + bn;
      }
      if (stv && (r - 2 >= 1)) {
        *(float4*)&gl[(r - 2) & 3][p0] = rA0;
        *(float4*)&gl[(r - 2) & 3][p0 + 4] = rA1;
      }
      rA0 = rB0; rA1 = rB1;
    }
  }
}

// ---------------- logZ per batch ----------------
__global__ void logz_k(const float* __restrict__ alpha, float* __restrict__ lz) {
  int b = blockIdx.x; int lane = threadIdx.x;
  float a = (lane < C_) ? alpha[((size_t)b * T_ + (T_ - 1)) * C_ + lane] : -3.0e38f;
  float m = a;
  #pragma unroll
  for (int o = 32; o > 0; o >>= 1) m = fmaxf(m, __shfl_xor(m, o));
  float e = (lane < C_) ? __expf(a - m) : 0.f;
  #pragma unroll
  for (int o = 32; o > 0; o >>= 1) e += __shfl_xor(e, o);
  if (lane == 0) lz[b] = m + __logf(e);
}

// ---------------- marginals = exp(alpha+beta-logZ) ----------------
__global__ void marg_k(const float* __restrict__ alpha, const float* __restrict__ beta,
                       const float* __restrict__ lz, float* __restrict__ out0) {
  size_t idx = (size_t)blockIdx.x * 256 + threadIdx.x;
  int b = (int)(idx / (T_ * C_));
  out0[idx] = __expf(alpha[idx] + beta[idx] - lz[b]);
}

extern "C" void kernel_launch(void* const* d_in, const int* in_sizes, int n_in,
                              void* d_out, int out_size, void* d_ws, size_t ws_size,
                              hipStream_t stream) {
  const int*   tok   = (const int*)d_in[0];
  const int*   seq   = (const int*)d_in[1];
  const float* emb   = (const float*)d_in[2];
  const float* Wih0  = (const float*)d_in[3];
  const float* Whh0  = (const float*)d_in[4];
  const float* bih0  = (const float*)d_in[5];
  const float* bhh0  = (const float*)d_in[6];
  const float* Wih0r = (const float*)d_in[7];
  const float* Whh0r = (const float*)d_in[8];
  const float* bih0r = (const float*)d_in[9];
  const float* bhh0r = (const float*)d_in[10];
  const float* Wih1  = (const float*)d_in[11];
  const float* Whh1  = (const float*)d_in[12];
  const float* bih1  = (const float*)d_in[13];
  const float* bhh1  = (const float*)d_in[14];
  const float* Wih1r = (const float*)d_in[15];
  const float* Whh1r = (const float*)d_in[16];
  const float* bih1r = (const float*)d_in[17];
  const float* bhh1r = (const float*)d_in[18];
  const float* fW    = (const float*)d_in[19];
  const float* fb    = (const float*)d_in[20];
  const float* gW    = (const float*)d_in[21];
  const float* gb    = (const float*)d_in[22];
  const float* h0    = (const float*)d_in[23];
  const float* c0    = (const float*)d_in[24];

  float* ws = (float*)d_ws;
  float* x0  = ws;                          // 4,194,304 floats
  u16*   xp  = (u16*)(ws + 4194304);        // 104,857,600 bf16
  u16*   x1  = (u16*)(ws + 109051904);      // 26,214,400 bf16
  float* lz  = ws + 135266304;              // 128 floats

  float* out   = (float*)d_out;
  float* f_out = out + 2621440;
  float* g_out = out + 5242880;
  float* a_out = out + 57671680;
  float* b_out = out + 60293120;

  embed_k<<<16384, 256, 0, stream>>>(tok, emb, x0);

  dim3 g400(1024, 7), g20(1024, 1);
  // layer 0 input projections (K=32): fp32 A -> bf16 xp
  gemm_mfma_t<0,1><<<g400, 256, 0, stream>>>(x0, Wih0,  bih0,  bhh0,  xp,                    32, 400, 400);
  gemm_mfma_t<0,1><<<g400, 256, 0, stream>>>(x0, Wih0r, bih0r, bhh0r, xp + (size_t)52428800, 32, 400, 400);
  lstm_scan<<<256, 512, 0, stream>>>(xp, Whh0, Whh0r, h0, c0, nullptr, x1, 0);
  // layer 1 input projections (K=200): bf16 A -> bf16 xp
  gemm_mfma_t<1,1><<<g400, 256, 0, stream>>>(x1, Wih1,  bih1,  bhh1,  xp,                    200, 400, 400);
  gemm_mfma_t<1,1><<<g400, 256, 0, stream>>>(x1, Wih1r, bih1r, bhh1r, xp + (size_t)52428800, 200, 400, 400);
  lstm_scan<<<256, 512, 0, stream>>>(xp, Whh1, Whh1r, h0, c0, seq, x1, 1);
  // emissions + transitions: bf16 A -> fp32 outputs
  gemm_mfma_t<1,0><<<g20,  256, 0, stream>>>(x1, fW, fb, nullptr, f_out, 200, 20,  20);
  gemm_mfma_t<1,0><<<g400, 256, 0, stream>>>(x1, gW, gb, nullptr, g_out, 200, 400, 400);
  // CRF forward/backward
  crf_k<<<256, 64, 0, stream>>>(f_out, g_out, a_out, b_out);
  logz_k<<<128, 64, 0, stream>>>(a_out, lz);
  marg_k<<<10240, 256, 0, stream>>>(a_out, b_out, lz, out);
}

// Round 27
// 2503.798 us; speedup vs baseline: 1.3075x; 1.1493x over previous
//
#include <hip/hip_runtime.h>
#include <hip/hip_bf16.h>

#define B_ 128
#define T_ 1024
#define E_ 32
#define H_ 100
#define C_ 20
#define M_ (B_*T_)   // 131072

typedef __attribute__((ext_vector_type(8))) short bf16x8v;
typedef __attribute__((ext_vector_type(4))) float f32x4v;
typedef __attribute__((ext_vector_type(2))) _Float16 h2v;
typedef unsigned short u16;
typedef unsigned int u32;

static __device__ __forceinline__ short f2b(float x) {   // float -> bf16 bits
  union { __hip_bfloat16 b; short s; } u;
  u.b = __float2bfloat16(x);
  return u.s;
}
static __device__ __forceinline__ float b2f(u16 x) {     // bf16 bits -> float
  return __uint_as_float(((u32)x) << 16);
}

#if __has_builtin(__builtin_amdgcn_fdot2)
#define FDOT2(w, p, c) __builtin_amdgcn_fdot2((w), (p), (c), false)
#else
static __device__ __forceinline__ float FDOT2(h2v w, h2v p, float c) {
  return fmaf((float)w[1], (float)p[1], fmaf((float)w[0], (float)p[0], c));
}
#endif

// Counted barrier: LDS-producer drain + raw barrier, WITHOUT the vmcnt(0)
// drain __syncthreads emits (r21: -77us/dispatch on the scan).
#define WGBAR() do {                                        \
    asm volatile("s_waitcnt lgkmcnt(0)" ::: "memory");      \
    __builtin_amdgcn_s_barrier();                           \
    __builtin_amdgcn_sched_barrier(0);                      \
  } while (0)

// ---------------- embedding lookup ----------------
__global__ void embed_k(const int* __restrict__ tok, const float* __restrict__ emb,
                        float* __restrict__ x0) {
  int idx = blockIdx.x * 256 + threadIdx.x;   // over M_*E_ = 4194304
  int bt = idx >> 5;
  int e  = idx & 31;
  x0[idx] = emb[tok[bt] * E_ + e];
}

// ---------------- bf16 MFMA GEMM: C[M,N] = A[M,K] @ W[N,K]^T + b1 + b2 ------
template<int ABF, int OBF>
__global__ __launch_bounds__(256) void gemm_mfma_t(
    const void* __restrict__ Av, const float* __restrict__ W,
    const float* __restrict__ b1, const float* __restrict__ b2,
    void* __restrict__ Cv, int K, int N, int ldc)
{
  __shared__ short as[64 * 40];   // [row][k] pad 40
  __shared__ short ws[64 * 40];   // [col][k]
  const float* Af = (const float*)Av;
  const u16*   Ab = (const u16*)Av;
  float* Cf = (float*)Cv;
  u16*   Cb = (u16*)Cv;
  int tid = threadIdx.x, lane = tid & 63, w = tid >> 6;
  int lr = lane & 15, lq = lane >> 4;
  size_t m0 = (size_t)blockIdx.x * 64;
  int n0 = blockIdx.y * 64;
  int srow = tid >> 2;            // staging row 0..63
  int sk = (tid & 3) * 8;         // staging k offset 0,8,16,24
  bool wok = (n0 + srow) < N;
  const float* Wp = wok ? (W + (size_t)(n0 + srow) * K + sk) : W;
  size_t arow = (m0 + srow) * (size_t)K;
  f32x4v acc[4];
  #pragma unroll
  for (int r = 0; r < 4; ++r) acc[r] = (f32x4v){0.f, 0.f, 0.f, 0.f};
  int ksteps = (K + 31) / 32;
  for (int ks = 0; ks < ksteps; ++ks) {
    int kk = ks * 32;
    bf16x8v av, wv;
    if (kk + sk + 7 < K) {
      if (ABF) {
        av = *(const bf16x8v*)(Ab + arow + kk + sk);
      } else {
        float4 a0 = *(const float4*)(Af + arow + kk + sk);
        float4 a1 = *(const float4*)(Af + arow + kk + sk + 4);
        av[0]=f2b(a0.x); av[1]=f2b(a0.y); av[2]=f2b(a0.z); av[3]=f2b(a0.w);
        av[4]=f2b(a1.x); av[5]=f2b(a1.y); av[6]=f2b(a1.z); av[7]=f2b(a1.w);
      }
      if (wok) {
        float4 w0 = *(const float4*)(Wp + kk);
        float4 w1 = *(const float4*)(Wp + kk + 4);
        wv[0]=f2b(w0.x); wv[1]=f2b(w0.y); wv[2]=f2b(w0.z); wv[3]=f2b(w0.w);
        wv[4]=f2b(w1.x); wv[5]=f2b(w1.y); wv[6]=f2b(w1.z); wv[7]=f2b(w1.w);
      } else {
        #pragma unroll
        for (int j = 0; j < 8; ++j) wv[j] = 0;
      }
    } else {
      #pragma unroll
      for (int j = 0; j < 8; ++j) {
        int k = kk + sk + j;
        av[j] = (k < K) ? (ABF ? (short)Ab[arow + k] : f2b(Af[arow + k])) : (short)0;
        wv[j] = (wok && k < K) ? f2b(W[(size_t)(n0 + srow) * K + k]) : (short)0;
      }
    }
    *(bf16x8v*)&as[srow * 40 + sk] = av;
    *(bf16x8v*)&ws[srow * 40 + sk] = wv;
    __syncthreads();
    bf16x8v bf = *(const bf16x8v*)&ws[(16 * w + lr) * 40 + 8 * lq];
    #pragma unroll
    for (int r = 0; r < 4; ++r) {
      bf16x8v af = *(const bf16x8v*)&as[(16 * r + lr) * 40 + 8 * lq];
      acc[r] = __builtin_amdgcn_mfma_f32_16x16x32_bf16(af, bf, acc[r], 0, 0, 0);
    }
    __syncthreads();
  }
  int col = n0 + 16 * w + lr;
  if (col < N) {
    float bv = (b1 ? b1[col] : 0.f) + (b2 ? b2[col] : 0.f);
    #pragma unroll
    for (int r = 0; r < 4; ++r)
      #pragma unroll
      for (int rg = 0; rg < 4; ++rg) {
        size_t off = (m0 + 16 * r + 4 * lq + rg) * (size_t)ldc + col;
        float v = acc[r][rg] + bv;
        if (OBF) Cb[off] = (u16)f2b(v); else Cf[off] = v;
      }
  }
}

// ---------------- LSTM scan, k-split f16 reg weights + counted barriers -----
// EXACT r21 winner (746us/dispatch, total 2506us -- best of 26 rounds).
// Ablation grid around it (r20 load-depth, r22 LDS-load, r23 store-batch,
// r25 co-schedule, r26 phase-balance) all neutral-to-negative: the scan is
// latency-structural (~1750cy/step serial chain x 1024 steps).
__global__ __launch_bounds__(512, 1) void lstm_scan(
    const u16* __restrict__ xp,
    const float* __restrict__ WhhF, const float* __restrict__ WhhR,
    const float* __restrict__ h0, const float* __restrict__ c0, // [4][B][H]
    const int* __restrict__ seqlen,   // null => no mask
    u16* __restrict__ outbuf,         // [B][T][200] bf16, dir*100 offset
    int layer)
{
  int wg = blockIdx.x; int dir = wg & 1; int b = wg >> 1;
  int tid = threadIdx.x;
  const float* Whh = dir ? WhhR : WhhF;
  const u16* xpp = xp + ((size_t)dir * B_ + b) * T_ * 400;
  const float* h0p = h0 + ((size_t)(2 * layer + dir) * B_ + b) * H_;
  const float* c0p = c0 + ((size_t)(2 * layer + dir) * B_ + b) * H_;
  __shared__ __align__(16) float gsh[400];
  __shared__ __align__(16) _Float16 hph[112];   // h as f16; [100..111] = 0
  bool act = (tid < 400);
  int r = tid >> 1, half = tid & 1;
  int bu = half * 24;   // base k-pair (u32) index
  u32 w0p[28], w1p[28];
  if (act) {
    const float* r0 = Whh + (size_t)(2 * r) * H_;
    const float* r1 = Whh + (size_t)(2 * r + 1) * H_;
    #pragma unroll
    for (int j = 0; j < 28; ++j) {
      int kp = bu + j;
      bool rl = half ? (j < 26) : (j < 24);
      int k = 2 * kp;
      float a0 = (rl && k < 100) ? r0[k] : 0.f;
      float a1 = (rl && k + 1 < 100) ? r0[k + 1] : 0.f;
      float b0 = (rl && k < 100) ? r1[k] : 0.f;
      float b1 = (rl && k + 1 < 100) ? r1[k + 1] : 0.f;
      w0p[j] = __builtin_bit_cast(u32, (h2v){(_Float16)a0, (_Float16)a1});
      w1p[j] = __builtin_bit_cast(u32, (h2v){(_Float16)b0, (_Float16)b1});
    }
    #pragma unroll
    for (int j = 0; j < 28; ++j)
      asm volatile("" : "+v"(w0p[j]), "+v"(w1p[j]));
  }
  if (tid < 112) hph[tid] = (_Float16)((tid < H_) ? h0p[tid] : 0.f);
  float c = (tid < H_) ? c0p[tid] : 0.f;
  int sl = seqlen ? seqlen[b] : T_;
  __syncthreads();
  int tstep = dir ? -1 : 1;
  int t0 = dir ? (T_ - 1) : 0;
  ushort2 xc = make_ushort2(0, 0), xn = make_ushort2(0, 0), x2 = make_ushort2(0, 0);
  bool ldx = act && !half;
  if (ldx) {
    xc = *(const ushort2*)(xpp + (size_t)t0 * 400 + 2 * r);
    xn = *(const ushort2*)(xpp + (size_t)(t0 + tstep) * 400 + 2 * r);
    x2 = *(const ushort2*)(xpp + (size_t)(t0 + 2 * tstep) * 400 + 2 * r);
  }
  for (int tt = 0; tt < T_; ++tt) {
    int t = t0 + tstep * tt;
    ushort2 x3 = make_ushort2(0, 0);
    if (ldx && tt + 3 < T_)
      x3 = *(const ushort2*)(xpp + (size_t)(t + 3 * tstep) * 400 + 2 * r);
    if (act) {
      float a0 = half ? 0.f : b2f(xc.x);
      float a1 = half ? 0.f : b2f(xc.y);
      #pragma unroll
      for (int q = 0; q < 7; ++q) {
        f32x4v hp = ((const f32x4v*)hph)[6 * half + q];   // 2 addrs/wave -> free
        #pragma unroll
        for (int i = 0; i < 4; ++i) {
          h2v p = __builtin_bit_cast(h2v, hp[i]);
          a0 = FDOT2(__builtin_bit_cast(h2v, w0p[4 * q + i]), p, a0);
          a1 = FDOT2(__builtin_bit_cast(h2v, w1p[4 * q + i]), p, a1);
        }
      }
      a0 += __shfl_xor(a0, 1);   // combine k-halves (adjacent lanes)
      a1 += __shfl_xor(a1, 1);
      if (!half) *(float2*)&gsh[2 * r] = make_float2(a0, a1);
    }
    WGBAR();
    if (tid < H_) {
      float gi = gsh[tid], gf = gsh[H_ + tid], gg = gsh[2 * H_ + tid], go = gsh[3 * H_ + tid];
      float si = 1.f / (1.f + __expf(-gi));
      float sf = 1.f / (1.f + __expf(-gf));
      float so = 1.f / (1.f + __expf(-go));
      float tg = 1.f - 2.f / (1.f + __expf(2.f * gg));
      c = fmaf(sf, c, si * tg);
      float tc = 1.f - 2.f / (1.f + __expf(2.f * c));
      float h = so * tc;
      hph[tid] = (_Float16)h;
      outbuf[((size_t)b * T_ + t) * 200 + dir * H_ + tid] = (t < sl) ? (u16)f2b(h) : (u16)0;
    }
    WGBAR();
    xc = xn; xn = x2; x2 = x3;
  }
}

// ---------------- CRF with LDS ring staging (r15 winner, unchanged) --------
__global__ __launch_bounds__(64) void crf_k(
    const float* __restrict__ f, const float* __restrict__ g,
    float* __restrict__ alpha, float* __restrict__ beta)
{
  int wg = blockIdx.x;
  int lane = threadIdx.x;
  __shared__ __align__(16) float gl[4][400];   // ring: row r -> slot r&3
  __shared__ __align__(16) float aw[20];       // alpha: a[t-1]; beta: f[t+1]+b[t+1]
  bool stv = lane < 50;
  int p0 = 8 * lane;                           // this lane stages floats [p0,p0+8)
  float4 rA0, rA1, rB0, rB1;                   // in-flight staged row (reg ring)

  if (wg < B_) {
    int b = wg;
    const float* fp = f + (size_t)b * T_ * C_;
    const float* gp = g + (size_t)b * T_ * C_ * C_;
    float* ap = alpha + (size_t)b * T_ * C_;
    if (lane < C_) {
      float a0 = fp[lane];
      ap[lane] = a0;
      aw[lane] = a0;
    }
    if (stv) {
      float4 v0 = *(const float4*)(gp + 400 + p0);
      float4 v1 = *(const float4*)(gp + 404 + p0);
      *(float4*)&gl[1 & 3][p0] = v0;  *(float4*)&gl[1 & 3][p0 + 4] = v1;
      v0 = *(const float4*)(gp + 800 + p0);
      v1 = *(const float4*)(gp + 804 + p0);
      *(float4*)&gl[2 & 3][p0] = v0;  *(float4*)&gl[2 & 3][p0 + 4] = v1;
      rA0 = *(const float4*)(gp + 1200 + p0);       // row 3 in flight
      rA1 = *(const float4*)(gp + 1204 + p0);
    }
    for (int t = 1; t < T_; ++t) {
      if (stv && (t + 3 < T_)) {
        rB0 = *(const float4*)(gp + (size_t)(t + 3) * 400 + p0);
        rB1 = *(const float4*)(gp + (size_t)(t + 3) * 400 + p0 + 4);
      }
      if (lane < C_) {
        const float* gr = &gl[t & 3][0];
        float ft = fp[(size_t)t * C_ + lane];
        float awv[20];
        #pragma unroll
        for (int q = 0; q < 5; ++q)
          *(f32x4v*)&awv[4 * q] = ((const f32x4v*)aw)[q];
        float s[20];
        #pragma unroll
        for (int i = 0; i < 20; ++i)
          s[i] = awv[i] + gr[i * 20 + lane];
        float m4[5];
        #pragma unroll
        for (int q = 0; q < 5; ++q)
          m4[q] = fmaxf(fmaxf(s[4*q], s[4*q+1]), fmaxf(s[4*q+2], s[4*q+3]));
        float m = fmaxf(fmaxf(m4[0], m4[1]), fmaxf(fmaxf(m4[2], m4[3]), m4[4]));
        float e4[5];
        #pragma unroll
        for (int q = 0; q < 5; ++q) {
          float e0 = __expf(s[4*q] - m),   e1 = __expf(s[4*q+1] - m);
          float e2 = __expf(s[4*q+2] - m), e3 = __expf(s[4*q+3] - m);
          e4[q] = (e0 + e1) + (e2 + e3);
        }
        float sum = (e4[0] + e4[1]) + ((e4[2] + e4[3]) + e4[4]);
        float an = ft + m + __logf(sum);
        ap[(size_t)t * C_ + lane] = an;
        aw[lane] = an;
      }
      if (stv && (t + 2 < T_)) {
        *(float4*)&gl[(t + 2) & 3][p0] = rA0;
        *(float4*)&gl[(t + 2) & 3][p0 + 4] = rA1;
      }
      rA0 = rB0; rA1 = rB1;
    }
  } else {
    int b = wg - B_;
    const float* fp = f + (size_t)b * T_ * C_;
    const float* gp = g + (size_t)b * T_ * C_ * C_;
    float* bp = beta + (size_t)b * T_ * C_;
    if (lane < C_) {
      bp[(size_t)(T_ - 1) * C_ + lane] = 0.f;
      aw[lane] = fp[(size_t)(T_ - 1) * C_ + lane];
    }
    if (stv) {
      float4 v0 = *(const float4*)(gp + (size_t)(T_ - 1) * 400 + p0);
      float4 v1 = *(const float4*)(gp + (size_t)(T_ - 1) * 400 + p0 + 4);
      *(float4*)&gl[(T_ - 1) & 3][p0] = v0;  *(float4*)&gl[(T_ - 1) & 3][p0 + 4] = v1;
      v0 = *(const float4*)(gp + (size_t)(T_ - 2) * 400 + p0);
      v1 = *(const float4*)(gp + (size_t)(T_ - 2) * 400 + p0 + 4);
      *(float4*)&gl[(T_ - 2) & 3][p0] = v0;  *(float4*)&gl[(T_ - 2) & 3][p0 + 4] = v1;
      rA0 = *(const float4*)(gp + (size_t)(T_ - 3) * 400 + p0);
      rA1 = *(const float4*)(gp + (size_t)(T_ - 3) * 400 + p0 + 4);
    }
    for (int u = 1; u < T_; ++u) {
      int t = T_ - 1 - u;
      int r = t + 1;
      if (stv && (r - 3 >= 1)) {
        rB0 = *(const float4*)(gp + (size_t)(r - 3) * 400 + p0);
        rB1 = *(const float4*)(gp + (size_t)(r - 3) * 400 + p0 + 4);
      }
      if (lane < C_) {
        const float* gr = &gl[r & 3][lane * 20];
        float fcur = fp[(size_t)t * C_ + lane];
        float awv[20];
        #pragma unroll
        for (int q = 0; q < 5; ++q)
          *(f32x4v*)&awv[4 * q] = ((const f32x4v*)aw)[q];
        float s[20];
        #pragma unroll
        for (int q = 0; q < 5; ++q) {
          f32x4v gq = *(const f32x4v*)&gr[4 * q];
          s[4*q]   = awv[4*q]   + gq[0];
          s[4*q+1] = awv[4*q+1] + gq[1];
          s[4*q+2] = awv[4*q+2] + gq[2];
          s[4*q+3] = awv[4*q+3] + gq[3];
        }
        float m4[5];
        #pragma unroll
        for (int q = 0; q < 5; ++q)
          m4[q] = fmaxf(fmaxf(s[4*q], s[4*q+1]), fmaxf(s[4*q+2], s[4*q+3]));
        float m = fmaxf(fmaxf(m4[0], m4[1]), fmaxf(fmaxf(m4[2], m4[3]), m4[4]));
        float e4[5];
        #pragma unroll
        for (int q = 0; q < 5; ++q) {
          float e0 = __expf(s[4*q] - m),   e1 = __expf(s[4*q+1] - m);
          float e2 = __expf(s[4*q+2] - m), e3 = __expf(s[4*q+3] - m);
          e4[q] = (e0 + e1) + (e2 + e3);
        }
        float sum = (e4[0] + e4[1]) + ((e4[2] + e4[3]) + e4[4]);
        float bn = m + __logf(sum);
        bp[(size_t)t * C_ + lane] = bn;
        aw[lane] = fcur + bn;
      }
      if (stv && (r - 2 >= 1)) {
        *(float4*)&gl[(r - 2) & 3][p0] = rA0;
        *(float4*)&gl[(r - 2) & 3][p0 + 4] = rA1;
      }
      rA0 = rB0; rA1 = rB1;
    }
  }
}

// ---------------- logZ per batch ----------------
__global__ void logz_k(const float* __restrict__ alpha, float* __restrict__ lz) {
  int b = blockIdx.x; int lane = threadIdx.x;
  float a = (lane < C_) ? alpha[((size_t)b * T_ + (T_ - 1)) * C_ + lane] : -3.0e38f;
  float m = a;
  #pragma unroll
  for (int o = 32; o > 0; o >>= 1) m = fmaxf(m, __shfl_xor(m, o));
  float e = (lane < C_) ? __expf(a - m) : 0.f;
  #pragma unroll
  for (int o = 32; o > 0; o >>= 1) e += __shfl_xor(e, o);
  if (lane == 0) lz[b] = m + __logf(e);
}

// ---------------- marginals = exp(alpha+beta-logZ) ----------------
__global__ void marg_k(const float* __restrict__ alpha, const float* __restrict__ beta,
                       const float* __restrict__ lz, float* __restrict__ out0) {
  size_t idx = (size_t)blockIdx.x * 256 + threadIdx.x;
  int b = (int)(idx / (T_ * C_));
  out0[idx] = __expf(alpha[idx] + beta[idx] - lz[b]);
}

extern "C" void kernel_launch(void* const* d_in, const int* in_sizes, int n_in,
                              void* d_out, int out_size, void* d_ws, size_t ws_size,
                              hipStream_t stream) {
  const int*   tok   = (const int*)d_in[0];
  const int*   seq   = (const int*)d_in[1];
  const float* emb   = (const float*)d_in[2];
  const float* Wih0  = (const float*)d_in[3];
  const float* Whh0  = (const float*)d_in[4];
  const float* bih0  = (const float*)d_in[5];
  const float* bhh0  = (const float*)d_in[6];
  const float* Wih0r = (const float*)d_in[7];
  const float* Whh0r = (const float*)d_in[8];
  const float* bih0r = (const float*)d_in[9];
  const float* bhh0r = (const float*)d_in[10];
  const float* Wih1  = (const float*)d_in[11];
  const float* Whh1  = (const float*)d_in[12];
  const float* bih1  = (const float*)d_in[13];
  const float* bhh1  = (const float*)d_in[14];
  const float* Wih1r = (const float*)d_in[15];
  const float* Whh1r = (const float*)d_in[16];
  const float* bih1r = (const float*)d_in[17];
  const float* bhh1r = (const float*)d_in[18];
  const float* fW    = (const float*)d_in[19];
  const float* fb    = (const float*)d_in[20];
  const float* gW    = (const float*)d_in[21];
  const float* gb    = (const float*)d_in[22];
  const float* h0    = (const float*)d_in[23];
  const float* c0    = (const float*)d_in[24];

  float* ws = (float*)d_ws;
  float* x0  = ws;                          // 4,194,304 floats
  u16*   xp  = (u16*)(ws + 4194304);        // 104,857,600 bf16
  u16*   x1  = (u16*)(ws + 109051904);      // 26,214,400 bf16
  float* lz  = ws + 135266304;              // 128 floats

  float* out   = (float*)d_out;
  float* f_out = out + 2621440;
  float* g_out = out + 5242880;
  float* a_out = out + 57671680;
  float* b_out = out + 60293120;

  embed_k<<<16384, 256, 0, stream>>>(tok, emb, x0);

  dim3 g400(2048, 7), g20(2048, 1);
  // layer 0 input projections (K=32): fp32 A -> bf16 xp
  gemm_mfma_t<0,1><<<g400, 256, 0, stream>>>(x0, Wih0,  bih0,  bhh0,  xp,                    32, 400, 400);
  gemm_mfma_t<0,1><<<g400, 256, 0, stream>>>(x0, Wih0r, bih0r, bhh0r, xp + (size_t)52428800, 32, 400, 400);
  lstm_scan<<<256, 512, 0, stream>>>(xp, Whh0, Whh0r, h0, c0, nullptr, x1, 0);
  // layer 1 input projections (K=200): bf16 A -> bf16 xp
  gemm_mfma_t<1,1><<<g400, 256, 0, stream>>>(x1, Wih1,  bih1,  bhh1,  xp,                    200, 400, 400);
  gemm_mfma_t<1,1><<<g400, 256, 0, stream>>>(x1, Wih1r, bih1r, bhh1r, xp + (size_t)52428800, 200, 400, 400);
  lstm_scan<<<256, 512, 0, stream>>>(xp, Whh1, Whh1r, h0, c0, seq, x1, 1);
  // emissions + transitions: bf16 A -> fp32 outputs
  gemm_mfma_t<1,0><<<g20,  256, 0, stream>>>(x1, fW, fb, nullptr, f_out, 200, 20,  20);
  gemm_mfma_t<1,0><<<g400, 256, 0, stream>>>(x1, gW, gb, nullptr, g_out, 200, 400, 400);
  // CRF forward/backward
  crf_k<<<256, 64, 0, stream>>>(f_out, g_out, a_out, b_out);
  logz_k<<<128, 64, 0, stream>>>(a_out, lz);
  marg_k<<<10240, 256, 0, stream>>>(a_out, b_out, lz, out);
}